// Round 3
// baseline (581.507 us; speedup 1.0000x reference)
//
#include <hip/hip_runtime.h>
#include <math.h>

// Problem constants
#define NPTS  32768      // 8 * 4096 points
#define NPAIR 4096       // 64 * 64 (oc,ic) pairs
#define NC    23         // basis combos
#define TPB   256
#define PPT   2                      // points per thread -> dwordx2 stores
#define PTS_PER_BLOCK (TPB * PPT)    // 512 points per block
#define PT    64                     // pair tile per block (j-loop length)

// ---------------- compile-time constant tables ----------------
namespace cgen {
constexpr double PI = 3.14159265358979323846264338327950288;
constexpr double fact(int n) { double r = 1; for (int i = 2; i <= n; ++i) r *= i; return r; }
constexpr double comb(int n, int k) { double r = 1; for (int i = 0; i < k; ++i) r = r * (n - i) / (i + 1); return r; }
constexpr double csqrt(double x) { double g = x > 1 ? x : 1.0; for (int i = 0; i < 100; ++i) g = 0.5 * (g + x / g); return g; }

struct Tables {
  int n[NC]; int l[NC]; int m[NC];
  double pref[NC];      // norm_r * Klm * (sqrt(2) if m != 0)
  double lag[NC][4];    // Laguerre poly coeffs (x^0..x^3)
};
constexpr Tables gen() {
  Tables t{};
  int idx = 0;
  for (int n = 1; n <= 4; ++n)
    for (int k = 0; k < 3; ++k)
      for (int m = -3; m <= 3; ++m) {
        int am = m < 0 ? -m : m;
        if (!(am <= k && k < n)) continue;
        t.n[idx] = n; t.l[idx] = k; t.m[idx] = m;
        double norm_r = csqrt((2.0 / n) * (2.0 / n) * (2.0 / n) * fact(n - k - 1) / (2.0 * n * fact(n + k)));
        double Klm = csqrt((2.0 * k + 1.0) / (4.0 * PI) * fact(k - am) / fact(k + am));
        t.pref[idx] = norm_r * Klm * (m != 0 ? csqrt(2.0) : 1.0);
        int kk = n - k - 1, a = 2 * k + 1;
        for (int i = 0; i < 4; ++i) t.lag[idx][i] = 0.0;
        for (int i = 0; i <= kk; ++i)
          t.lag[idx][i] = ((i & 1) ? -1.0 : 1.0) * comb(kk + a, kk - i) / fact(i);
        ++idx;
      }
  return t;
}
constexpr Tables T = gen();
} // namespace cgen

// ---------------- SGPR coefficient rows via scalar loads ----------------
typedef float f16v __attribute__((ext_vector_type(16)));
typedef float f8v  __attribute__((ext_vector_type(8)));

// Load one 23-float coef row into SGPRs. Second load overlaps at dword 15
// (byte 0x3c) so the pair covers dwords 0..22 with no out-of-bounds access:
// last row base = 4095*92, +0x3c+32B = 376832 = exact buffer end.
__device__ __forceinline__ void sload_row(const float* p, f16v& a, f8v& b) {
  asm volatile("s_load_dwordx16 %0, %2, 0x0\n\t"
               "s_load_dwordx8  %1, %2, 0x3c"
               : "=&s"(a), "=&s"(b)
               : "s"(p));
}

// Reliable SMEM wait (SMEM returns out-of-order; only lgkmcnt(0) is valid).
// Tied "+s" operands create the data dependency so consumers can't hoist.
#define GATE(A, B) asm volatile("s_waitcnt lgkmcnt(0)" : "+s"(A), "+s"(B))

// ---------------- kernel ----------------
__global__ __launch_bounds__(TPB, 4)
void dcconv_poly_einsum(const float* __restrict__ pos,
                        const float* __restrict__ coef,
                        float* __restrict__ out) {
  const int tid   = threadIdx.x;
  const int pt0   = blockIdx.x * PTS_PER_BLOCK + tid * PPT;  // 2 consecutive points
  const int pair0 = blockIdx.y * PT;

  // ---- per-point geometry + 23 basis values, 2 points per thread ----
  const float2* __restrict__ pv = reinterpret_cast<const float2*>(pos + (size_t)pt0 * 3);
  const float2 f0 = pv[0], f1 = pv[1], f2 = pv[2];
  // layout: f0={x0,y0} f1={z0,x1} f2={y1,z1}

  float p0[NC], p1[NC];

  auto evalpt = [&](float x, float y, float z, float (&pc)[NC]) {
    const float rxy2 = x * x + y * y;
    const float r    = sqrtf(rxy2 + z * z) + 1e-12f;
    const float ct   = z / r;
    const float st   = sqrtf(rxy2) / r;        // == sqrt(clip(1-ct^2)), >= 0
    const float st2  = st * st;
    const float invq = rsqrtf(fmaxf(rxy2, 1e-30f));
    const float cp   = x * invq;
    const float sp   = y * invq;
    const float c2p  = (cp - sp) * (cp + sp);
    const float s2p  = 2.0f * sp * cp;

    float rho[5]; rho[0] = 0.0f; rho[1] = 2.0f * r; rho[2] = r; rho[3] = (2.0f / 3.0f) * r; rho[4] = 0.5f * r;
    float en[5];  en[0] = 0.0f;
    en[4] = expf(-0.25f * r);
    en[2] = en[4] * en[4];
    en[1] = en[2] * en[2];
    en[3] = expf(-(1.0f / 3.0f) * r);

    float P[3][3] = {};
    P[0][0] = 1.0f;
    P[1][0] = ct;                    P[1][1] = -st;
    P[2][0] = 1.5f * ct * ct - 0.5f; P[2][1] = -3.0f * ct * st; P[2][2] = 3.0f * st2;

    float trig[5]; trig[0] = s2p; trig[1] = sp; trig[2] = 1.0f; trig[3] = cp; trig[4] = c2p;

#pragma unroll
    for (int c = 0; c < NC; ++c) {
      const int n = cgen::T.n[c], l = cgen::T.l[c], m = cgen::T.m[c];
      const int am = m < 0 ? -m : m;
      const float rh = rho[n];
      const float L = (float)cgen::T.lag[c][0]
                    + rh * ((float)cgen::T.lag[c][1]
                    + rh * ((float)cgen::T.lag[c][2]
                    + rh *  (float)cgen::T.lag[c][3]));
      const float rl = (l == 0) ? 1.0f : ((l == 1) ? rh : rh * rh);
      pc[c] = (float)cgen::T.pref[c] * en[n] * rl * L * P[l][am] * trig[m + 2];
    }
  };

  evalpt(f0.x, f0.y, f1.x, p0);
  evalpt(f1.y, f2.x, f2.y, p1);

  // ---- einsum: coef rows in SGPRs (s_load double-buffer), pure v_fmac inner loop ----
  float* optr = out + (size_t)pair0 * NPTS + pt0;

  // 4 accumulator chains (even/odd split) so fmac latency (~4cy) is covered
  auto dot_store = [&](const f16v& CA, const f8v& CB) {
    float e0 = 0.f, o0 = 0.f, e1 = 0.f, o1 = 0.f;
#pragma unroll
    for (int c = 0; c < 16; c += 2) {
      e0 = fmaf(CA[c],     p0[c],     e0);
      e1 = fmaf(CA[c],     p1[c],     e1);
      o0 = fmaf(CA[c + 1], p0[c + 1], o0);
      o1 = fmaf(CA[c + 1], p1[c + 1], o1);
    }
#pragma unroll
    for (int c = 16; c < NC; c += 2) {      // coef c -> CB[c-15]  (CB[0] is dup of c15)
      e0 = fmaf(CB[c - 15], p0[c], e0);
      e1 = fmaf(CB[c - 15], p1[c], e1);
      if (c + 1 < NC) {
        o0 = fmaf(CB[c - 14], p0[c + 1], o0);
        o1 = fmaf(CB[c - 14], p1[c + 1], o1);
      }
    }
    float2 res; res.x = e0 + o0; res.y = e1 + o1;
    *reinterpret_cast<float2*>(optr) = res;
    optr += NPTS;
  };

  const float* rp = coef + (size_t)pair0 * NC;   // row j base (wave-uniform)
  f16v A0, B0; f8v A1, B1;
  sload_row(rp, A0, A1);                         // prologue: row 0 in flight

#pragma unroll 1
  for (int j = 0; j < PT; j += 2) {
    GATE(A0, A1);                    // waits only A (B not yet issued)
    sload_row(rp + NC, B0, B1);      // issue row j+1; hides under A's FMAs
    __builtin_amdgcn_sched_barrier(0);
    dot_store(A0, A1);               // row j

    GATE(B0, B1);
    const float* rpn = rp + ((j + 2 < PT) ? 2 * NC : NC);  // clamp: never past last row
    sload_row(rpn, A0, A1);          // issue row j+2 (or re-load last row, harmless)
    __builtin_amdgcn_sched_barrier(0);
    dot_store(B0, B1);               // row j+1
    rp = rpn;
  }
  asm volatile("s_waitcnt lgkmcnt(0)");   // drain the final (unused) prefetch
}

// ---------------- launch ----------------
extern "C" void kernel_launch(void* const* d_in, const int* in_sizes, int n_in,
                              void* d_out, int out_size, void* d_ws, size_t ws_size,
                              hipStream_t stream) {
  const float* pos  = (const float*)d_in[0];   // (8, 4096, 3) fp32
  const float* coef = (const float*)d_in[1];   // (64, 64, 23) fp32
  float* out = (float*)d_out;                  // (64, 64, 8, 4096) fp32

  dim3 grid(NPTS / PTS_PER_BLOCK, NPAIR / PT); // (64, 64) = 4096 blocks
  dim3 block(TPB);
  hipLaunchKernelGGL(dcconv_poly_einsum, grid, block, 0, stream, pos, coef, out);
}